// Round 1
// baseline (868.789 us; speedup 1.0000x reference)
//
#include <hip/hip_runtime.h>

// Quantized 2x conv pipeline, exact integer arithmetic.
// All fake_quant scales are powers of two, so reference fp32 math is exact
// integer math: we reproduce it bit-exactly in int8 + fp32-integer accumulators.
//
// ws layout:
//   [0      .. 256)        : consts (16 floats): [0]=1/s_in, [1]=s_in*s_w1/s_o1,
//                            [2]=s_o1*s_w2/s_o2, [3]=s_o2
//   [256    .. )            : w1f (450 floats, layout [c][kh][oc][kw])
//                            b1f (10), w2f (900, [c][kh][oc][kw]), b2f (10)
//   [8192   .. +41943296)   : x_int8  [32][5][512][512] (+256 pad)
//   [41951488 .. +83558400) : yq_int8 [32][10][510][512] (row stride 512, padded)

#define XQ_OFF   8192
#define YQ_OFF   41951488ULL

__device__ __forceinline__ float qclamp(float v) {
    return fminf(fmaxf(v, -128.0f), 127.0f);
}

__global__ __launch_bounds__(256) void prep_kernel(
    const float* __restrict__ w1, const float* __restrict__ b1,
    const float* __restrict__ w2, const float* __restrict__ b2,
    const float* __restrict__ s_in, const float* __restrict__ s_w1,
    const float* __restrict__ s_o1, const float* __restrict__ s_w2,
    const float* __restrict__ s_o2,
    float* __restrict__ consts, float* __restrict__ w1f, float* __restrict__ b1f,
    float* __restrict__ w2f, float* __restrict__ b2f)
{
    int t = threadIdx.x;
    float si = s_in[0], sw1 = s_w1[0], so1 = s_o1[0], sw2 = s_w2[0], so2 = s_o2[0];
    if (t == 0) {
        consts[0] = 1.0f / si;
        consts[1] = (si * sw1) / so1;   // 2^-7, exact
        consts[2] = (so1 * sw2) / so2;  // 2^-7, exact
        consts[3] = so2;
    }
    // w1: OIHW [10][5][3][3] -> [c][kh][oc][kw]
    for (int i = t; i < 450; i += 256) {
        int oc = i / 45, rem = i % 45;
        int c = rem / 9, kh = (rem % 9) / 3, kw = rem % 3;
        float q = qclamp(rintf(w1[i] / sw1));
        w1f[((c * 3 + kh) * 10 + oc) * 3 + kw] = q;
    }
    for (int i = t; i < 10; i += 256)
        b1f[i] = qclamp(rintf(b1[i] / (si * sw1)));
    // w2: [10][10][3][3] -> [c][kh][oc][kw]
    for (int i = t; i < 900; i += 256) {
        int oc = i / 90, rem = i % 90;
        int c = rem / 9, kh = (rem % 9) / 3, kw = rem % 3;
        float q = qclamp(rintf(w2[i] / sw2));
        w2f[((c * 3 + kh) * 10 + oc) * 3 + kw] = q;
    }
    for (int i = t; i < 10; i += 256)
        b2f[i] = qclamp(rintf(b2[i] / (so1 * sw2)));
}

__global__ __launch_bounds__(256) void quant_x_kernel(
    const float4* __restrict__ x, const float* __restrict__ consts,
    int* __restrict__ xq, int n4)
{
    int i = blockIdx.x * 256 + threadIdx.x;
    if (i >= n4) return;
    float inv = consts[0];
    float4 v = x[i];
    int q0 = (int)qclamp(rintf(v.x * inv));
    int q1 = (int)qclamp(rintf(v.y * inv));
    int q2 = (int)qclamp(rintf(v.z * inv));
    int q3 = (int)qclamp(rintf(v.w * inv));
    xq[i] = (q0 & 255) | ((q1 & 255) << 8) | ((q2 & 255) << 16) | (q3 << 24);
}

// conv1: in [32][5][512][512] int8, VALID 3x3 -> requant -> yq [32][10][510][512(pad)]
__global__ __launch_bounds__(256) void conv1_kernel(
    const signed char* __restrict__ xq, const float* __restrict__ wf,
    const float* __restrict__ bf, const float* __restrict__ consts,
    signed char* __restrict__ yq)
{
    int t = blockIdx.x * 256 + threadIdx.x;
    int owt = t & 127;          // 128 tiles of 4 pixels (tile 127 partial)
    int r = t >> 7;
    int oh = r % 510;
    int n = r / 510;            // grid sized exactly: n < 32
    int ow0 = owt << 2;

    float acc[10][4];
    #pragma unroll
    for (int oc = 0; oc < 10; ++oc) {
        float b = bf[oc];
        acc[oc][0] = b; acc[oc][1] = b; acc[oc][2] = b; acc[oc][3] = b;
    }

    const signed char* xb = xq + (size_t)n * (5 * 512 * 512) + oh * 512 + ow0;
    #pragma unroll
    for (int c = 0; c < 5; ++c) {
        #pragma unroll
        for (int kh = 0; kh < 3; ++kh) {
            const signed char* p = xb + c * 262144 + kh * 512;
            int u0 = *(const int*)p;
            int u1 = *(const int*)(p + 4);
            float f[6];
            f[0] = (float)(signed char)(u0);
            f[1] = (float)(signed char)(u0 >> 8);
            f[2] = (float)(signed char)(u0 >> 16);
            f[3] = (float)(signed char)(u0 >> 24);
            f[4] = (float)(signed char)(u1);
            f[5] = (float)(signed char)(u1 >> 8);
            const float* wrow = wf + (c * 3 + kh) * 30;
            #pragma unroll
            for (int oc = 0; oc < 10; ++oc) {
                float w0 = wrow[oc * 3 + 0];
                float w1 = wrow[oc * 3 + 1];
                float w2 = wrow[oc * 3 + 2];
                #pragma unroll
                for (int j = 0; j < 4; ++j)
                    acc[oc][j] = fmaf(f[j], w0,
                                 fmaf(f[j + 1], w1,
                                 fmaf(f[j + 2], w2, acc[oc][j])));
            }
        }
    }

    float cr1 = consts[1];
    if (owt < 127) {
        #pragma unroll
        for (int oc = 0; oc < 10; ++oc) {
            int q0 = (int)qclamp(rintf(acc[oc][0] * cr1));
            int q1 = (int)qclamp(rintf(acc[oc][1] * cr1));
            int q2 = (int)qclamp(rintf(acc[oc][2] * cr1));
            int q3 = (int)qclamp(rintf(acc[oc][3] * cr1));
            size_t idx = (((size_t)(n * 10 + oc) * 510) + oh) * 512 + ow0;
            *(int*)(yq + idx) = (q0 & 255) | ((q1 & 255) << 8) |
                                ((q2 & 255) << 16) | (q3 << 24);
        }
    } else {
        // tail tile: ow 508,509 valid only
        #pragma unroll
        for (int oc = 0; oc < 10; ++oc) {
            size_t idx = (((size_t)(n * 10 + oc) * 510) + oh) * 512 + ow0;
            yq[idx + 0] = (signed char)(int)qclamp(rintf(acc[oc][0] * cr1));
            yq[idx + 1] = (signed char)(int)qclamp(rintf(acc[oc][1] * cr1));
        }
    }
}

// conv2: yq [32][10][510][512(pad)] int8, VALID 3x3 -> out fp32 [32][10][508][508]
__global__ __launch_bounds__(256) void conv2_kernel(
    const signed char* __restrict__ yq, const float* __restrict__ wf,
    const float* __restrict__ bf, const float* __restrict__ consts,
    float* __restrict__ out)
{
    int t = blockIdx.x * 256 + threadIdx.x;
    int owt = t % 127;          // 127 tiles of 4 pixels (508 = 127*4, exact)
    int r = t / 127;
    int oh = r % 508;
    int n = r / 508;
    if (n >= 32) return;
    int ow0 = owt << 2;

    float acc[10][4];
    #pragma unroll
    for (int oc = 0; oc < 10; ++oc) {
        float b = bf[oc];
        acc[oc][0] = b; acc[oc][1] = b; acc[oc][2] = b; acc[oc][3] = b;
    }

    const signed char* yb = yq + (size_t)n * (10 * 510 * 512) + (size_t)oh * 512 + ow0;
    #pragma unroll
    for (int c = 0; c < 10; ++c) {
        #pragma unroll
        for (int kh = 0; kh < 3; ++kh) {
            const signed char* p = yb + (size_t)c * (510 * 512) + kh * 512;
            int u0 = *(const int*)p;
            int u1 = *(const int*)(p + 4);
            float f[6];
            f[0] = (float)(signed char)(u0);
            f[1] = (float)(signed char)(u0 >> 8);
            f[2] = (float)(signed char)(u0 >> 16);
            f[3] = (float)(signed char)(u0 >> 24);
            f[4] = (float)(signed char)(u1);
            f[5] = (float)(signed char)(u1 >> 8);
            const float* wrow = wf + (c * 3 + kh) * 30;
            #pragma unroll
            for (int oc = 0; oc < 10; ++oc) {
                float w0 = wrow[oc * 3 + 0];
                float w1 = wrow[oc * 3 + 1];
                float w2 = wrow[oc * 3 + 2];
                #pragma unroll
                for (int j = 0; j < 4; ++j)
                    acc[oc][j] = fmaf(f[j], w0,
                                 fmaf(f[j + 1], w1,
                                 fmaf(f[j + 2], w2, acc[oc][j])));
            }
        }
    }

    float cr2 = consts[2];
    float so = consts[3];
    #pragma unroll
    for (int oc = 0; oc < 10; ++oc) {
        float4 v;
        v.x = qclamp(rintf(acc[oc][0] * cr2)) * so;
        v.y = qclamp(rintf(acc[oc][1] * cr2)) * so;
        v.z = qclamp(rintf(acc[oc][2] * cr2)) * so;
        v.w = qclamp(rintf(acc[oc][3] * cr2)) * so;
        size_t idx = (((size_t)(n * 10 + oc) * 508) + oh) * 508 + ow0;
        *(float4*)(out + idx) = v;
    }
}

extern "C" void kernel_launch(void* const* d_in, const int* in_sizes, int n_in,
                              void* d_out, int out_size, void* d_ws, size_t ws_size,
                              hipStream_t stream) {
    const float* x    = (const float*)d_in[0];
    const float* w1   = (const float*)d_in[1];
    const float* b1   = (const float*)d_in[2];
    const float* w2   = (const float*)d_in[3];
    const float* b2   = (const float*)d_in[4];
    const float* s_in = (const float*)d_in[5];
    const float* s_w1 = (const float*)d_in[6];
    const float* s_o1 = (const float*)d_in[7];
    const float* s_w2 = (const float*)d_in[8];
    const float* s_o2 = (const float*)d_in[9];

    char* ws = (char*)d_ws;
    float* consts = (float*)ws;                 // 16 floats
    float* w1f = (float*)(ws + 256);            // 450
    float* b1f = w1f + 450;                     // 10
    float* w2f = b1f + 10;                      // 900
    float* b2f = w2f + 900;                     // 10
    signed char* xqb = (signed char*)(ws + XQ_OFF);
    signed char* yqb = (signed char*)(ws + YQ_OFF);

    prep_kernel<<<1, 256, 0, stream>>>(w1, b1, w2, b2, s_in, s_w1, s_o1, s_w2, s_o2,
                                       consts, w1f, b1f, w2f, b2f);

    int n4 = 32 * 5 * 512 * 512 / 4;            // 10,485,760 float4 groups
    quant_x_kernel<<<(n4 + 255) / 256, 256, 0, stream>>>(
        (const float4*)x, consts, (int*)xqb, n4);

    // conv1: 32 * 510 * 128 threads = 2,088,960 -> 8160 blocks exactly
    conv1_kernel<<<8160, 256, 0, stream>>>(xqb, w1f, b1f, consts, yqb);

    // conv2: 32 * 508 * 127 threads = 2,064,512 -> 8065 blocks (tail guarded)
    conv2_kernel<<<8065, 256, 0, stream>>>(yqb, w2f, b2f, consts, (float*)d_out);
}

// Round 2
// 585.955 us; speedup vs baseline: 1.4827x; 1.4827x over previous
//
#include <hip/hip_runtime.h>

// Quantized 2x conv pipeline, exact integer arithmetic via v_dot4_i32_i8.
// All fake_quant scales are powers of two, so reference fp32 math is exact
// integer math: int8 operands, int32 accumulators, float requant (exact,
// |acc| < 2^24). kw=3 window -> dot4 with zero 4th weight byte; sliding
// activation windows via v_alignbyte_b32.
//
// ws layout:
//   [0    ..   64) : consts (floats): [0]=1/s_in, [1]=(s_in*s_w1)/s_o1,
//                    [2]=(s_o1*s_w2)/s_o2, [3]=s_o2
//   [256  ..  856) : wp1 (150 ints, [c][kh][oc] packed w0|w1|w2|0)
//   [1280 .. 1320) : b1i (10 ints)
//   [2048 .. 3248) : wp2 (300 ints, [c][kh][oc])
//   [3584 .. 3624) : b2i (10 ints)
//   [8192      .. ) : x_int8 [32][5][512][512]
//   [41951488  .. ) : yq_int8 [32][10][510][512] (row stride 512, padded)

#define XQ_OFF   8192
#define YQ_OFF   41951488ULL

__device__ __forceinline__ float qclamp(float v) {
    return fminf(fmaxf(v, -128.0f), 127.0f);
}

__device__ __forceinline__ int dot4(int a, int b, int c) {
#if __has_builtin(__builtin_amdgcn_sdot4)
    return __builtin_amdgcn_sdot4(a, b, c, false);
#else
    c += ((a << 24) >> 24) * ((b << 24) >> 24);
    c += ((a << 16) >> 24) * ((b << 16) >> 24);
    c += ((a <<  8) >> 24) * ((b <<  8) >> 24);
    c += (a >> 24) * (b >> 24);
    return c;
#endif
}

__device__ __forceinline__ int alignb(int hi, int lo, int sh) {
#if __has_builtin(__builtin_amdgcn_alignbyte)
    return __builtin_amdgcn_alignbyte(hi, lo, sh);
#else
    return (int)((((unsigned long long)(unsigned)hi << 32) | (unsigned)lo) >> (8 * sh));
#endif
}

__global__ __launch_bounds__(256) void prep_kernel(
    const float* __restrict__ w1, const float* __restrict__ b1,
    const float* __restrict__ w2, const float* __restrict__ b2,
    const float* __restrict__ s_in, const float* __restrict__ s_w1,
    const float* __restrict__ s_o1, const float* __restrict__ s_w2,
    const float* __restrict__ s_o2,
    float* __restrict__ consts, int* __restrict__ wp1, int* __restrict__ b1i,
    int* __restrict__ wp2, int* __restrict__ b2i)
{
    int t = threadIdx.x;
    float si = s_in[0], sw1 = s_w1[0], so1 = s_o1[0], sw2 = s_w2[0], so2 = s_o2[0];
    if (t == 0) {
        consts[0] = 1.0f / si;
        consts[1] = (si * sw1) / so1;   // 2^-7, exact
        consts[2] = (so1 * sw2) / so2;  // 2^-7, exact
        consts[3] = so2;
    }
    // w1 OIHW [10][5][3][3] -> wp1[(c*3+kh)*10+oc] = bytes(w0,w1,w2,0)
    for (int i = t; i < 150; i += 256) {
        int oc = i / 15, rem = i % 15, c = rem / 3, kh = rem % 3;
        const float* src = w1 + (((oc * 5 + c) * 3 + kh) * 3);
        int q0 = (int)qclamp(rintf(src[0] / sw1));
        int q1 = (int)qclamp(rintf(src[1] / sw1));
        int q2 = (int)qclamp(rintf(src[2] / sw1));
        wp1[(c * 3 + kh) * 10 + oc] = (q0 & 255) | ((q1 & 255) << 8) | ((q2 & 255) << 16);
    }
    for (int i = t; i < 10; i += 256)
        b1i[i] = (int)qclamp(rintf(b1[i] / (si * sw1)));
    // w2 [10][10][3][3] -> wp2[(c*3+kh)*10+oc]
    for (int i = t; i < 300; i += 256) {
        int oc = i / 30, rem = i % 30, c = rem / 3, kh = rem % 3;
        const float* src = w2 + (((oc * 10 + c) * 3 + kh) * 3);
        int q0 = (int)qclamp(rintf(src[0] / sw2));
        int q1 = (int)qclamp(rintf(src[1] / sw2));
        int q2 = (int)qclamp(rintf(src[2] / sw2));
        wp2[(c * 3 + kh) * 10 + oc] = (q0 & 255) | ((q1 & 255) << 8) | ((q2 & 255) << 16);
    }
    for (int i = t; i < 10; i += 256)
        b2i[i] = (int)qclamp(rintf(b2[i] / (so1 * sw2)));
}

__global__ __launch_bounds__(256) void quant_x_kernel(
    const float4* __restrict__ x, const float* __restrict__ consts,
    int* __restrict__ xq, int n4)
{
    int i = blockIdx.x * 256 + threadIdx.x;
    if (i >= n4) return;
    float inv = consts[0];
    float4 v = x[i];
    int q0 = (int)qclamp(rintf(v.x * inv));
    int q1 = (int)qclamp(rintf(v.y * inv));
    int q2 = (int)qclamp(rintf(v.z * inv));
    int q3 = (int)qclamp(rintf(v.w * inv));
    xq[i] = (q0 & 255) | ((q1 & 255) << 8) | ((q2 & 255) << 16) | (q3 << 24);
}

// conv1: xq [32][5][512][512] int8, VALID 3x3 -> requant -> yq [32][10][510][512(pad)]
__global__ __launch_bounds__(256) void conv1_kernel(
    const signed char* __restrict__ xq, const int* __restrict__ wp,
    const int* __restrict__ bi, const float* __restrict__ consts,
    signed char* __restrict__ yq)
{
    int t = blockIdx.x * 256 + threadIdx.x;
    int owt = t & 127;          // 128 tiles of 4 pixels (tile 127 partial)
    int r = t >> 7;
    int oh = r % 510;
    int n = r / 510;            // grid sized exactly: n < 32
    int ow0 = owt << 2;

    int acc[10][4];
    #pragma unroll
    for (int oc = 0; oc < 10; ++oc) {
        int b = bi[oc];
        acc[oc][0] = b; acc[oc][1] = b; acc[oc][2] = b; acc[oc][3] = b;
    }

    const signed char* xb = xq + (size_t)n * (5 * 512 * 512) + oh * 512 + ow0;
    #pragma unroll
    for (int c = 0; c < 5; ++c) {
        #pragma unroll
        for (int kh = 0; kh < 3; ++kh) {
            const int* pi = (const int*)(xb + c * 262144 + kh * 512);
            int u0 = pi[0];
            int u1 = pi[1];
            int win0 = u0;
            int win1 = alignb(u1, u0, 1);
            int win2 = alignb(u1, u0, 2);
            int win3 = alignb(u1, u0, 3);
            const int* wrow = wp + (c * 3 + kh) * 10;
            #pragma unroll
            for (int oc = 0; oc < 10; ++oc) {
                int w = wrow[oc];
                acc[oc][0] = dot4(win0, w, acc[oc][0]);
                acc[oc][1] = dot4(win1, w, acc[oc][1]);
                acc[oc][2] = dot4(win2, w, acc[oc][2]);
                acc[oc][3] = dot4(win3, w, acc[oc][3]);
            }
        }
    }

    float cr1 = consts[1];
    if (owt < 127) {
        #pragma unroll
        for (int oc = 0; oc < 10; ++oc) {
            int q0 = (int)qclamp(rintf((float)acc[oc][0] * cr1));
            int q1 = (int)qclamp(rintf((float)acc[oc][1] * cr1));
            int q2 = (int)qclamp(rintf((float)acc[oc][2] * cr1));
            int q3 = (int)qclamp(rintf((float)acc[oc][3] * cr1));
            size_t idx = (((size_t)(n * 10 + oc) * 510) + oh) * 512 + ow0;
            *(int*)(yq + idx) = (q0 & 255) | ((q1 & 255) << 8) |
                                ((q2 & 255) << 16) | (q3 << 24);
        }
    } else {
        // tail tile: ow 508,509 valid only
        #pragma unroll
        for (int oc = 0; oc < 10; ++oc) {
            size_t idx = (((size_t)(n * 10 + oc) * 510) + oh) * 512 + ow0;
            yq[idx + 0] = (signed char)(int)qclamp(rintf((float)acc[oc][0] * cr1));
            yq[idx + 1] = (signed char)(int)qclamp(rintf((float)acc[oc][1] * cr1));
        }
    }
}

// conv2: yq [32][10][510][512(pad)] int8, VALID 3x3 -> out fp32 [32][10][508][508]
__global__ __launch_bounds__(256) void conv2_kernel(
    const signed char* __restrict__ yq, const int* __restrict__ wp,
    const int* __restrict__ bi, const float* __restrict__ consts,
    float* __restrict__ out)
{
    int t = blockIdx.x * 256 + threadIdx.x;
    int owt = t % 127;          // 127 tiles of 4 pixels (508 = 127*4, exact)
    int r = t / 127;
    int oh = r % 508;
    int n = r / 508;
    if (n >= 32) return;
    int ow0 = owt << 2;

    int acc[10][4];
    #pragma unroll
    for (int oc = 0; oc < 10; ++oc) {
        int b = bi[oc];
        acc[oc][0] = b; acc[oc][1] = b; acc[oc][2] = b; acc[oc][3] = b;
    }

    const signed char* yb = yq + (size_t)n * (10 * 510 * 512) + (size_t)oh * 512 + ow0;
    #pragma unroll
    for (int c = 0; c < 10; ++c) {
        #pragma unroll
        for (int kh = 0; kh < 3; ++kh) {
            const int* pi = (const int*)(yb + (size_t)c * (510 * 512) + kh * 512);
            int u0 = pi[0];
            int u1 = pi[1];
            int win0 = u0;
            int win1 = alignb(u1, u0, 1);
            int win2 = alignb(u1, u0, 2);
            int win3 = alignb(u1, u0, 3);
            const int* wrow = wp + (c * 3 + kh) * 10;
            #pragma unroll
            for (int oc = 0; oc < 10; ++oc) {
                int w = wrow[oc];
                acc[oc][0] = dot4(win0, w, acc[oc][0]);
                acc[oc][1] = dot4(win1, w, acc[oc][1]);
                acc[oc][2] = dot4(win2, w, acc[oc][2]);
                acc[oc][3] = dot4(win3, w, acc[oc][3]);
            }
        }
    }

    float cr2 = consts[2];
    float so = consts[3];
    #pragma unroll
    for (int oc = 0; oc < 10; ++oc) {
        float4 v;
        v.x = qclamp(rintf((float)acc[oc][0] * cr2)) * so;
        v.y = qclamp(rintf((float)acc[oc][1] * cr2)) * so;
        v.z = qclamp(rintf((float)acc[oc][2] * cr2)) * so;
        v.w = qclamp(rintf((float)acc[oc][3] * cr2)) * so;
        size_t idx = (((size_t)(n * 10 + oc) * 508) + oh) * 508 + ow0;
        *(float4*)(out + idx) = v;
    }
}

extern "C" void kernel_launch(void* const* d_in, const int* in_sizes, int n_in,
                              void* d_out, int out_size, void* d_ws, size_t ws_size,
                              hipStream_t stream) {
    const float* x    = (const float*)d_in[0];
    const float* w1   = (const float*)d_in[1];
    const float* b1   = (const float*)d_in[2];
    const float* w2   = (const float*)d_in[3];
    const float* b2   = (const float*)d_in[4];
    const float* s_in = (const float*)d_in[5];
    const float* s_w1 = (const float*)d_in[6];
    const float* s_o1 = (const float*)d_in[7];
    const float* s_w2 = (const float*)d_in[8];
    const float* s_o2 = (const float*)d_in[9];

    char* ws = (char*)d_ws;
    float* consts = (float*)ws;                 // 16 floats
    int* wp1 = (int*)(ws + 256);                // 150
    int* b1i = (int*)(ws + 1280);               // 10
    int* wp2 = (int*)(ws + 2048);               // 300
    int* b2i = (int*)(ws + 3584);               // 10
    signed char* xqb = (signed char*)(ws + XQ_OFF);
    signed char* yqb = (signed char*)(ws + YQ_OFF);

    prep_kernel<<<1, 256, 0, stream>>>(w1, b1, w2, b2, s_in, s_w1, s_o1, s_w2, s_o2,
                                       consts, wp1, b1i, wp2, b2i);

    int n4 = 32 * 5 * 512 * 512 / 4;            // 10,485,760 float4 groups
    quant_x_kernel<<<(n4 + 255) / 256, 256, 0, stream>>>(
        (const float4*)x, consts, (int*)xqb, n4);

    // conv1: 32 * 510 * 128 threads = 2,088,960 -> 8160 blocks exactly
    conv1_kernel<<<8160, 256, 0, stream>>>(xqb, wp1, b1i, consts, yqb);

    // conv2: 32 * 508 * 127 threads = 2,064,512 -> 8065 blocks (tail guarded)
    conv2_kernel<<<8065, 256, 0, stream>>>(yqb, wp2, b2i, consts, (float*)d_out);
}